// Round 8
// baseline (115331.641 us; speedup 1.0000x reference)
//
#include <hip/hip_runtime.h>
#include <math.h>

// Problem constants
constexpr int Bb = 64, Tt = 500, Ee = 256, Aa = 128, Dd = 400;
constexpr int STEPS = 500, Rr = 5;

// ws layout in ushort units
constexpr size_t W16_OFF = 4096000;            // after ep16 [64][500][128]
constexpr int O_P1 = 0;                        // W_p1  [400][256]
constexpr int O_P2 = 102400;                   // W_p2  [256][128]
constexpr int O_DEC = 135168;                  // W_dec [256][128]
constexpr int O_G = 167936;                    // Wg    [640][768] = [W_ix;W_ih]
constexpr int O_OUT = 659456;                  // W_out [512][400]
constexpr int W16_TOTAL = 864256;

typedef float f4v __attribute__((ext_vector_type(4)));
__device__ __forceinline__ f4v ntl4(const float* p) {
  return __builtin_nontemporal_load((const f4v*)p);
}
__device__ __forceinline__ ushort f2bf(float f) {      // RNE f32->bf16
  unsigned u = __float_as_uint(f);
  u += 0x7FFFu + ((u >> 16) & 1u);
  return (ushort)(u >> 16);
}
__device__ __forceinline__ float bfl(unsigned u) { return __uint_as_float(u << 16); }
__device__ __forceinline__ float bfh(unsigned u) { return __uint_as_float(u & 0xFFFF0000u); }

// ---------------------------------------------------------------------------
// One-time weight conversion to bf16 (Wg = [W_ix(384); W_ih(256)] x 768)
// ---------------------------------------------------------------------------
__global__ __launch_bounds__(512)
void k_cvt(const float* __restrict__ W_p1, const float* __restrict__ W_p2,
           const float* __restrict__ W_dec, const float* __restrict__ W_ix,
           const float* __restrict__ W_ih, const float* __restrict__ W_out,
           ushort* __restrict__ w16) {
  int i = blockIdx.x * 512 + threadIdx.x;
  if (i >= W16_TOTAL) return;
  float v;
  if (i < O_P2)       v = W_p1[i];
  else if (i < O_DEC) v = W_p2[i - O_P2];
  else if (i < O_G)   v = W_dec[i - O_DEC];
  else if (i < O_OUT) {
    int j = i - O_G, k = j / 768, c = j % 768;
    v = (k < 384) ? W_ix[(size_t)k * 768 + c] : W_ih[(size_t)(k - 384) * 768 + c];
  } else              v = W_out[i - O_OUT];
  w16[i] = f2bf(v);
}

// ---------------------------------------------------------------------------
// Pre-kernel: enc_proj (bf16 out) = enc_feat @ W_enc
// ---------------------------------------------------------------------------
__global__ __launch_bounds__(512)
void k_encproj(const float* __restrict__ enc_feat,
               const float* __restrict__ W_enc,
               ushort* __restrict__ ep16) {
  __shared__ float sFeat[16][256];
  const int b = blockIdx.x, tg = blockIdx.y;
  const int t0 = tg * 16;
  const int tid = threadIdx.x;
  #pragma unroll
  for (int i = 0; i < 8; ++i) {
    int idx = tid + i * 512;
    int r = idx >> 8, c = idx & 255;
    int t = t0 + r;
    sFeat[r][c] = (t < Tt) ? enc_feat[((size_t)b * Tt + t) * Ee + c] : 0.0f;
  }
  __syncthreads();
  const int a = tid & 127, tl = tid >> 7;
  float acc0 = 0.f, acc1 = 0.f, acc2 = 0.f, acc3 = 0.f;
  #pragma unroll 4
  for (int k = 0; k < Ee; ++k) {
    float w = W_enc[k * Aa + a];
    acc0 = fmaf(sFeat[tl][k],      w, acc0);
    acc1 = fmaf(sFeat[tl + 4][k],  w, acc1);
    acc2 = fmaf(sFeat[tl + 8][k],  w, acc2);
    acc3 = fmaf(sFeat[tl + 12][k], w, acc3);
  }
  float accs[4] = {acc0, acc1, acc2, acc3};
  #pragma unroll
  for (int i = 0; i < 4; ++i) {
    int t = t0 + tl + 4 * i;
    if (t < Tt) ep16[((size_t)b * Tt + t) * Aa + a] = f2bf(accs[i]);
  }
}

// ---------------------------------------------------------------------------
// bf16-weight GEMV fragment: KS k-iters, NB-deep double-buffered uint2 loads
// (4 bf16 columns per load). fp32 accumulate. All indices compile-time.
// ---------------------------------------------------------------------------
template<int KS, int NB>
__device__ __forceinline__ float4 dotq_db16(const ushort* __restrict__ W, const int ldW,
                                            const float* __restrict__ x) {
  float4 acc = {0.f, 0.f, 0.f, 0.f};
  constexpr int NC = KS / NB;
  constexpr int TL = KS - NC * NB;
  uint2 A[NB], B[NB];
  if constexpr (NC > 0) {
    #pragma unroll
    for (int j = 0; j < NB; ++j) A[j] = *(const uint2*)(W + (size_t)j * ldW);
  }
  #pragma unroll
  for (int c = 0; c < NC; ++c) {
    uint2* cur = (c & 1) ? B : A;
    uint2* nxt = (c & 1) ? A : B;
    if (c + 1 < NC) {
      const ushort* Wn = W + (size_t)((c + 1) * NB) * ldW;
      #pragma unroll
      for (int j = 0; j < NB; ++j) nxt[j] = *(const uint2*)(Wn + (size_t)j * ldW);
    } else if constexpr (TL > 0) {
      const ushort* Wn = W + (size_t)(NC * NB) * ldW;
      #pragma unroll
      for (int j = 0; j < TL; ++j) nxt[j] = *(const uint2*)(Wn + (size_t)j * ldW);
    }
    const float* xb = x + c * NB;
    #pragma unroll
    for (int j = 0; j < NB; ++j) {
      float xv = xb[j];
      acc.x = fmaf(xv, bfl(cur[j].x), acc.x);
      acc.y = fmaf(xv, bfh(cur[j].x), acc.y);
      acc.z = fmaf(xv, bfl(cur[j].y), acc.z);
      acc.w = fmaf(xv, bfh(cur[j].y), acc.w);
    }
  }
  if constexpr (TL > 0) {
    uint2* cur = (NC & 1) ? B : A;
    if constexpr (NC == 0) {
      #pragma unroll
      for (int j = 0; j < TL; ++j) cur[j] = *(const uint2*)(W + (size_t)j * ldW);
    }
    const float* xb = x + NC * NB;
    #pragma unroll
    for (int j = 0; j < TL; ++j) {
      float xv = xb[j];
      acc.x = fmaf(xv, bfl(cur[j].x), acc.x);
      acc.y = fmaf(xv, bfh(cur[j].x), acc.y);
      acc.z = fmaf(xv, bfl(cur[j].y), acc.z);
      acc.w = fmaf(xv, bfh(cur[j].y), acc.w);
    }
  }
  return acc;
}

__device__ __forceinline__ float sigmoid_acc(float x) {
  float e = __expf(-x);
  return 1.0f / (1.0f + e);
}
__device__ __forceinline__ float tanh_acc(float x) {
  float cx = fminf(9.5f, fmaxf(-9.5f, x));
  float e = __expf(2.0f * cx);
  return (e - 1.0f) / (e + 1.0f);
}
__device__ __forceinline__ float tanh_fast(float x) {
  float cx = fminf(9.5f, fmaxf(-9.5f, x));
  float e = __expf(2.0f * cx);
  return (e - 1.0f) * __builtin_amdgcn_rcpf(e + 1.0f);
}

// ---------------------------------------------------------------------------
// Persistent decoder: 64 blocks x 512 threads (R1 structure), bf16 streams.
// ---------------------------------------------------------------------------
__global__ __launch_bounds__(512, 2)
void k_decoder(const float* __restrict__ enc_feat,
               const ushort* __restrict__ ep16all,
               const ushort* __restrict__ w16,
               const float* __restrict__ b_p1, const float* __restrict__ b_p2,
               const float* __restrict__ b_ix, const float* __restrict__ b_ih,
               const float* __restrict__ b_attn, const float* __restrict__ v_attn,
               const float* __restrict__ b_out,
               float* __restrict__ pred_out, float* __restrict__ attn_out) {
  __shared__ __align__(16) float sPred[400];
  __shared__ __align__(16) float sXt[640];    // [x(128) | ctx(256) | h(256)]
  __shared__ __align__(16) float sL1[256];
  __shared__ __align__(16) float sCat[512];   // [h(256) | ctx(256)] for P10
  __shared__ __align__(16) float sSd[128];
  __shared__ __align__(16) float sScore[512];
  __shared__ __align__(16) float sRaw[400];
  __shared__ __align__(16) float sRZ[512];
  __shared__ __align__(16) float sTmp[2048];
  __shared__ float sRed[8];

  const int b = blockIdx.x;
  const int tid = threadIdx.x;
  const int lane = tid & 63, wid = tid >> 6;
  const int l4 = tid & 3;

  // ---- init state
  for (int i = tid; i < 400; i += 512) sPred[i] = 0.f;
  for (int i = tid; i < 640; i += 512) sXt[i] = 0.f;
  if (tid < 512) sCat[tid] = 0.f;

  // ---- constants in registers
  float4 vq[8];
  #pragma unroll
  for (int i = 0; i < 8; ++i) vq[i] = *(const float4*)(v_attn + 4 * (l4 + 4 * i));

  float bP1 = 0.f, bIN = 0.f, bHN = 0.f;
  if (tid < 256) {
    bP1 = b_p1[tid];
    bIN = b_ix[512 + tid];
    bHN = b_ih[512 + tid];
  }
  const float bRZ = b_ix[tid] + b_ih[tid];    // cols 0..511 (r then z)
  float bP2 = 0.f, bAt = 0.f;
  if (tid < 128) { bP2 = b_p2[tid]; bAt = b_attn[tid]; }
  float bOut = 0.f;
  if (tid < 400) bOut = b_out[tid];

  // ---- per-thread GEMV geometry
  // P1: W_p1 [400][256]: 64 quads x 8 slices KS=50
  const ushort* w1 = w16 + O_P1 + 4 * (tid & 63) + (size_t)((tid >> 6) * 50) * 256;
  const float* x1 = sPred + (tid >> 6) * 50;
  // P2: W_p2 [256][128]: 32 quads x 16 slices KS=16
  const ushort* w2 = w16 + O_P2 + 4 * (tid & 31) + (size_t)((tid >> 5) * 16) * 128;
  const float* x2 = sL1 + (tid >> 5) * 16;
  // P6: W_dec same shape; x = new h (sXt[384:])
  const ushort* w6 = w16 + O_DEC + 4 * (tid & 31) + (size_t)((tid >> 5) * 16) * 128;
  const float* x6 = sXt + 384 + (tid >> 5) * 16;
  // G1: combined r/z cols 0..511 over concat K=640: 128 quads x 4 slices KS=160
  const ushort* wg1 = w16 + O_G + 4 * (tid & 127) + (size_t)((tid >> 7) * 160) * 768;
  const float* xg1 = sXt + (tid >> 7) * 160;
  // G2: n-gate cols 512..767. i_n (tid<256): 64 quads x 4 slices KS=96 (k<384)
  //     h_n (tid>=256): 64 quads x 4 slices KS=64 (k>=384)
  const int qa = tid & 63, sa = (tid >> 6) & 3;
  const ushort* wg2i = w16 + O_G + 512 + 4 * qa + (size_t)(sa * 96) * 768;
  const float* xg2i = sXt + sa * 96;
  const ushort* wg2h = w16 + O_G + 512 + 4 * qa + (size_t)(384 + sa * 64) * 768;
  const float* xg2h = sXt + 384 + sa * 64;
  // P10: W_out [512][400]: 100 quads x 4 slices KS=128 (400 active)
  const int q10 = tid % 100, s10 = tid / 100;
  const ushort* w10 = w16 + O_OUT + 4 * q10 + (size_t)(s10 * 128) * 400;
  const float* x10 = sCat + s10 * 128;
  // P7: enc_proj bf16 for this row
  const ushort* ep16 = ep16all + (size_t)b * Tt * Aa;
  const int g7 = tid >> 2;
  // P9: 64 e-quads x 8 t-slices of 63 (last 59); nontemporal fp32
  const int e4i = tid & 63, sl9 = tid >> 6;
  const int t9a = sl9 * 63;
  const int t9b = (t9a + 63 < Tt) ? (t9a + 63) : Tt;
  const float* fb9 = enc_feat + (size_t)b * Tt * Ee + 4 * e4i;

  __syncthreads();

  for (int t = 0; t < STEPS; ++t) {
    // ======== P1: l1 = relu(pred @ W_p1 + b_p1) ========
    { float4 a = dotq_db16<50, 10>(w1, 256, x1); *(float4*)&sTmp[tid * 4] = a; }
    __syncthreads();
    if (tid < 256) {
      float v = bP1;
      #pragma unroll
      for (int s = 0; s < 8; ++s) v += sTmp[s * 256 + tid];
      sL1[tid] = fmaxf(v, 0.f);
    }
    __syncthreads();

    // ======== P2: x = relu(l1 @ W_p2 + b_p2) -> sXt[0:128] ========
    { float4 a = dotq_db16<16, 16>(w2, 128, x2); *(float4*)&sTmp[tid * 4] = a; }
    __syncthreads();
    if (tid < 128) {
      float v = bP2;
      #pragma unroll
      for (int s = 0; s < 16; ++s) v += sTmp[s * 128 + tid];
      sXt[tid] = fmaxf(v, 0.f);
    }
    __syncthreads();

    // ======== G1: combined r/z pre-activations over concat [x|ctx|h] ======
    { float4 a = dotq_db16<160, 16>(wg1, 768, xg1); *(float4*)&sTmp[tid * 4] = a; }
    __syncthreads();
    {
      float v = bRZ;
      #pragma unroll
      for (int s = 0; s < 4; ++s) v += sTmp[s * 512 + tid];
      sRZ[tid] = sigmoid_acc(v);
    }
    __syncthreads();

    // ======== G2: i_n / h_n partials; h update ========
    {
      float4 a;
      if (tid < 256) a = dotq_db16<96, 16>(wg2i, 768, xg2i);
      else           a = dotq_db16<64, 16>(wg2h, 768, xg2h);
      *(float4*)&sTmp[tid * 4] = a;
    }
    __syncthreads();
    if (tid < 256) {
      float vin = bIN, vhn = bHN;
      #pragma unroll
      for (int s = 0; s < 4; ++s) vin += sTmp[s * 256 + tid];
      #pragma unroll
      for (int s = 0; s < 4; ++s) vhn += sTmp[1024 + s * 256 + tid];
      float r = sRZ[tid];
      float z = sRZ[256 + tid];
      float n = tanh_acc(vin + r * vhn);
      float hn = (1.f - z) * n + z * sXt[384 + tid];
      sXt[384 + tid] = hn;
      sCat[tid] = hn;
    }
    __syncthreads();

    // ======== P6: sd = h @ W_dec + b_attn ========
    { float4 a = dotq_db16<16, 16>(w6, 128, x6); *(float4*)&sTmp[tid * 4] = a; }
    __syncthreads();
    if (tid < 128) {
      float v = bAt;
      #pragma unroll
      for (int s = 0; s < 16; ++s) v += sTmp[s * 128 + tid];
      sSd[tid] = v;
    }
    __syncthreads();

    // ======== P7: scores from bf16 enc_proj ========
    {
      float4 sdq[8];
      #pragma unroll
      for (int i = 0; i < 8; ++i) sdq[i] = *(const float4*)(sSd + 4 * (l4 + 4 * i));
      #pragma unroll
      for (int p = 0; p < 4; ++p) {
        int tt = g7 + (p << 7);
        float acc = 0.f;
        if (tt < Tt) {
          const ushort* epb = ep16 + (size_t)tt * Aa + 4 * l4;
          #pragma unroll
          for (int i = 0; i < 8; ++i) {
            uint2 u = *(const uint2*)(epb + 16 * i);
            acc = fmaf(vq[i].x, tanh_fast(bfl(u.x) + sdq[i].x), acc);
            acc = fmaf(vq[i].y, tanh_fast(bfh(u.x) + sdq[i].y), acc);
            acc = fmaf(vq[i].z, tanh_fast(bfl(u.y) + sdq[i].z), acc);
            acc = fmaf(vq[i].w, tanh_fast(bfh(u.y) + sdq[i].w), acc);
          }
        }
        acc += __shfl_xor(acc, 1);
        acc += __shfl_xor(acc, 2);
        if (l4 == 0 && tt < Tt) sScore[tt] = acc;
      }
      __syncthreads();
    }

    // ======== P8: softmax over T; record attn ========
    {
      float val = (tid < Tt) ? sScore[tid] : -3.0e38f;
      float m = val;
      #pragma unroll
      for (int off = 32; off >= 1; off >>= 1) m = fmaxf(m, __shfl_xor(m, off));
      if (lane == 0) sRed[wid] = m;
      __syncthreads();
      float bm = sRed[0];
      #pragma unroll
      for (int w = 1; w < 8; ++w) bm = fmaxf(bm, sRed[w]);
      float e = (tid < Tt) ? __expf(val - bm) : 0.f;
      float ssum = e;
      #pragma unroll
      for (int off = 32; off >= 1; off >>= 1) ssum += __shfl_xor(ssum, off);
      __syncthreads();
      if (lane == 0) sRed[wid] = ssum;
      __syncthreads();
      float S = 0.f;
      #pragma unroll
      for (int w = 0; w < 8; ++w) S += sRed[w];
      if (tid < Tt) {
        float attn = e / S;
        sScore[tid] = attn;
        attn_out[((size_t)b * STEPS + t) * Tt + tid] = attn;
      }
      __syncthreads();
    }

    // ======== P9: ctx = attn @ enc_feat (fp32, nontemporal) ========
    {
      float accx = 0.f, accy = 0.f, accz = 0.f, accw = 0.f;
      #pragma unroll 8
      for (int tt = t9a; tt < t9b; ++tt) {
        float a = sScore[tt];
        f4v f = ntl4(fb9 + (size_t)tt * Ee);
        accx = fmaf(a, f.x, accx); accy = fmaf(a, f.y, accy);
        accz = fmaf(a, f.z, accz); accw = fmaf(a, f.w, accw);
      }
      float4 o = {accx, accy, accz, accw};
      *(float4*)&sTmp[tid * 4] = o;
      __syncthreads();
      if (tid < 256) {
        float v = 0.f;
        #pragma unroll
        for (int s = 0; s < 8; ++s) v += sTmp[s * 256 + tid];
        sXt[128 + tid] = v;
        sCat[256 + tid] = v;
      }
      __syncthreads();
    }

    // ======== P10: raw = [h,ctx] @ W_out + b_out ========
    if (tid < 400) { float4 a = dotq_db16<128, 16>(w10, 400, x10); *(float4*)&sTmp[tid * 4] = a; }
    __syncthreads();
    if (tid < 400) {
      float v = bOut;
      #pragma unroll
      for (int s = 0; s < 4; ++s) v += sTmp[s * 400 + tid];
      sRaw[tid] = v;
    }
    __syncthreads();

    // ======== P11: pred = chunked softmax(raw, 5x80) ========
    {
      if (wid < Rr) {
        int d0 = wid * 80 + lane;
        float v0 = sRaw[d0];
        float v1 = (lane < 16) ? sRaw[d0 + 64] : -3.0e38f;
        float m = fmaxf(v0, v1);
        #pragma unroll
        for (int off = 32; off >= 1; off >>= 1) m = fmaxf(m, __shfl_xor(m, off));
        float e0 = __expf(v0 - m);
        float e1 = (lane < 16) ? __expf(v1 - m) : 0.f;
        float s = e0 + e1;
        #pragma unroll
        for (int off = 32; off >= 1; off >>= 1) s += __shfl_xor(s, off);
        float inv = 1.0f / s;
        float p0 = e0 * inv;
        sPred[d0] = p0;
        pred_out[((size_t)b * STEPS + t) * Dd + d0] = p0;
        if (lane < 16) {
          float p1 = e1 * inv;
          sPred[d0 + 64] = p1;
          pred_out[((size_t)b * STEPS + t) * Dd + d0 + 64] = p1;
        }
      }
      __syncthreads();
    }
  }
}

// ---------------------------------------------------------------------------
extern "C" void kernel_launch(void* const* d_in, const int* in_sizes, int n_in,
                              void* d_out, int out_size, void* d_ws, size_t ws_size,
                              hipStream_t stream) {
  const float* enc_feat = (const float*)d_in[0];
  const float* W_p1  = (const float*)d_in[1];
  const float* b_p1  = (const float*)d_in[2];
  const float* W_p2  = (const float*)d_in[3];
  const float* b_p2  = (const float*)d_in[4];
  const float* W_ix  = (const float*)d_in[5];
  const float* W_ih  = (const float*)d_in[6];
  const float* b_ix  = (const float*)d_in[7];
  const float* b_ih  = (const float*)d_in[8];
  const float* W_dec = (const float*)d_in[9];
  const float* W_enc = (const float*)d_in[10];
  const float* b_attn= (const float*)d_in[11];
  const float* v_attn= (const float*)d_in[12];
  const float* W_out = (const float*)d_in[13];
  const float* b_out = (const float*)d_in[14];

  float* pred_out = (float*)d_out;                          // [64,500,400]
  float* attn_out = pred_out + (size_t)Bb * STEPS * Dd;     // [64,500,500]

  ushort* ep16 = (ushort*)d_ws;                             // [64][500][128]
  ushort* w16  = (ushort*)d_ws + W16_OFF;

  k_cvt<<<1688, 512, 0, stream>>>(W_p1, W_p2, W_dec, W_ix, W_ih, W_out, w16);
  k_encproj<<<dim3(Bb, 32), 512, 0, stream>>>(enc_feat, W_enc, ep16);
  k_decoder<<<Bb, 512, 0, stream>>>(enc_feat, ep16, w16,
                                    b_p1, b_p2, b_ix, b_ih,
                                    b_attn, v_attn, b_out,
                                    pred_out, attn_out);
}